// Round 2
// baseline (370.302 us; speedup 1.0000x reference)
//
#include <hip/hip_runtime.h>

// Problem constants (fixed by setup_inputs): B=256, N=512.
constexpr int B = 256;
constexpr int NELEM = 512 * 512;          // elements per batch
constexpr int BLOCKS_PER_B = 8;           // partial-sum blocks per batch (2048 blocks)
constexpr int THREADS = 256;
constexpr int F4_PER_BLOCK = NELEM / 4 / BLOCKS_PER_B;   // 8192 float4 per block
constexpr int F4_PER_THREAD = F4_PER_BLOCK / THREADS;    // 32
constexpr float MARGIN = 0.5f;
constexpr int NUM_PAIRS = B * (B - 1) / 2;               // 32640

// Stage 1: per-(batch, chunk) partial sums. Streaming float4-coalesced read.
// unroll 2 x 4-wide body = 8 loads in flight / thread; 4 independent
// accumulators break the FMA dependence chain. __launch_bounds__(256,4)
// caps VGPRs at 128 (no spill risk), 16 waves/CU — plenty for BW.
__global__ void __launch_bounds__(THREADS, 4) gsim_partial_kernel(
    const float* __restrict__ graph, float* __restrict__ partials) {
    const int b   = blockIdx.x >> 3;       // / BLOCKS_PER_B
    const int blk = blockIdx.x & 7;        // % BLOCKS_PER_B
    const float4* __restrict__ src = reinterpret_cast<const float4*>(graph)
        + (size_t)b * (NELEM / 4) + (size_t)blk * F4_PER_BLOCK + threadIdx.x;

    float s0 = 0.0f, s1 = 0.0f, s2 = 0.0f, s3 = 0.0f;
#pragma unroll 2
    for (int it = 0; it < F4_PER_THREAD; it += 4) {
        float4 a = src[(size_t)(it + 0) * THREADS];
        float4 c = src[(size_t)(it + 1) * THREADS];
        float4 d = src[(size_t)(it + 2) * THREADS];
        float4 e = src[(size_t)(it + 3) * THREADS];
        s0 += (a.x + a.y) + (a.z + a.w);
        s1 += (c.x + c.y) + (c.z + c.w);
        s2 += (d.x + d.y) + (d.z + d.w);
        s3 += (e.x + e.y) + (e.z + e.w);
    }
    float sum = (s0 + s1) + (s2 + s3);

    // wave (64-lane) shuffle reduce
#pragma unroll
    for (int off = 32; off > 0; off >>= 1)
        sum += __shfl_down(sum, off, 64);

    __shared__ float wsum[THREADS / 64];
    const int lane = threadIdx.x & 63;
    const int wid  = threadIdx.x >> 6;
    if (lane == 0) wsum[wid] = sum;
    __syncthreads();
    if (threadIdx.x == 0)
        partials[blockIdx.x] = (wsum[0] + wsum[1]) + (wsum[2] + wsum[3]);
}

// Stage 2: one block. Finish means, pairwise hinge loss over upper triangle.
// Thread t<128 handles rows t and (255-t): lengths (255-t)+t = 255 — balanced.
__global__ void __launch_bounds__(THREADS) finalize_kernel(
    const float* __restrict__ partials, const int* __restrict__ labels,
    float* __restrict__ out) {
    __shared__ float gs[B];
    __shared__ int   lab[B];
    const int t = threadIdx.x;

    float s = 0.0f;
#pragma unroll
    for (int k = 0; k < BLOCKS_PER_B; ++k)
        s += partials[t * BLOCKS_PER_B + k];
    gs[t]  = s * (1.0f / (float)NELEM);
    lab[t] = labels[t];
    __syncthreads();

    float acc = 0.0f;
    if (t < B / 2) {
        // row t  (j = t+1 .. 255)
        {
            const float gi = gs[t];
            const int   li = lab[t];
            for (int j = t + 1; j < B; ++j) {
                const float sim = gi * gs[j];
                acc += (li == lab[j]) ? fmaxf(MARGIN - sim, 0.0f)
                                      : fmaxf(sim - (1.0f - MARGIN), 0.0f);
            }
        }
        // row (B-1-t)  (j = B-t .. 255)
        {
            const int   i2 = B - 1 - t;
            const float gi = gs[i2];
            const int   li = lab[i2];
            for (int j = i2 + 1; j < B; ++j) {
                const float sim = gi * gs[j];
                acc += (li == lab[j]) ? fmaxf(MARGIN - sim, 0.0f)
                                      : fmaxf(sim - (1.0f - MARGIN), 0.0f);
            }
        }
    }

#pragma unroll
    for (int off = 32; off > 0; off >>= 1)
        acc += __shfl_down(acc, off, 64);

    __shared__ float wsum[THREADS / 64];
    if ((t & 63) == 0) wsum[t >> 6] = acc;
    __syncthreads();
    if (t == 0)
        out[0] = ((wsum[0] + wsum[1]) + (wsum[2] + wsum[3]))
                 * (1.0f / (float)NUM_PAIRS);
}

extern "C" void kernel_launch(void* const* d_in, const int* in_sizes, int n_in,
                              void* d_out, int out_size, void* d_ws, size_t ws_size,
                              hipStream_t stream) {
    const float* graph  = (const float*)d_in[0];   // [B, 512, 512] fp32
    const int*   labels = (const int*)d_in[1];     // [B] int
    float* out = (float*)d_out;                    // scalar fp32
    float* partials = (float*)d_ws;                // B * BLOCKS_PER_B floats

    gsim_partial_kernel<<<B * BLOCKS_PER_B, THREADS, 0, stream>>>(graph, partials);
    finalize_kernel<<<1, THREADS, 0, stream>>>(partials, labels, out);
}